// Round 1
// baseline (1466.257 us; speedup 1.0000x reference)
//
#include <hip/hip_runtime.h>
#include <math.h>

typedef short bf16x8 __attribute__((ext_vector_type(8)));
typedef float f32x4 __attribute__((ext_vector_type(4)));

union BF { unsigned u[4]; bf16x8 v; };

__device__ __forceinline__ unsigned pk2(float a, float b) {
  unsigned ua = __float_as_uint(a), ub = __float_as_uint(b);
  ua = (ua + 0x7FFFu + ((ua >> 16) & 1u)) >> 16;
  ub = (ub + 0x7FFFu + ((ub >> 16) & 1u)) >> 16;
  return (ua & 0xFFFFu) | (ub << 16);
}

// Weight fragment buffer layout (bf16 units):
//  attn mats a=0..7 (uWq,uWk,uWv,uWp,mWq,mWk,mWv,mWp): base a*4096, frag (m*2+f)
//  fW1: base 32768, frags (m*2+f), m=0..15
//  fW2: base 49152, frags (m*8+f), m=0..3, f=0..7
// Each frag block: 64 lanes x 8 bf16; element (lane,j) = W[k][n],
//  n = 16*m + (lane&15), k = 32*f + 4*(lane>>4) + (j&3) + 16*(j>>2)
#define OFF_F1 32768
#define OFF_F2 49152

__global__ __launch_bounds__(256) void prep_w(
    const float* __restrict__ uWq, const float* __restrict__ uWk,
    const float* __restrict__ uWv, const float* __restrict__ uWp,
    const float* __restrict__ mWq, const float* __restrict__ mWk,
    const float* __restrict__ mWv, const float* __restrict__ mWp,
    const float* __restrict__ fW1, const float* __restrict__ fW2,
    unsigned short* __restrict__ ws)
{
  int e = blockIdx.x * blockDim.x + threadIdx.x;   // 0..8191
  if (e >= 8192) return;
  int lane = e & 63;
  int fb   = e >> 6;                               // 0..127
  int g = lane >> 4, li = lane & 15;
  unsigned short outv[8];
#pragma unroll
  for (int j = 0; j < 8; ++j) {
    float val;
    if (fb < 64) {
      int a  = fb >> 3;
      int mf = fb & 7;
      int m = mf >> 1, f = mf & 1;
      int k = f*32 + 4*g + (j&3) + 16*(j>>2);
      int n = 16*m + li;
      const float* W =
        (a==0)?uWq:(a==1)?uWk:(a==2)?uWv:(a==3)?uWp:
        (a==4)?mWq:(a==5)?mWk:(a==6)?mWv:mWp;
      if ((a & 3) != 3) val = W[(n>>3)*512 + k*8 + (n&7)];   // [H,D,HS]
      else              val = W[k*64 + n];                   // [D,D]
    } else if (fb < 96) {
      int mf = fb - 64;
      int m = mf >> 1, f = mf & 1;
      int k = f*32 + 4*g + (j&3) + 16*(j>>2);
      int n = 16*m + li;
      val = fW1[k*256 + n];                                  // [64,256]
    } else {
      int mf = fb - 96;
      int m = mf >> 3, f = mf & 7;
      int k = f*32 + 4*g + (j&3) + 16*(j>>2);
      int n = 16*m + li;
      val = fW2[k*64 + n];                                   // [256,64]
    }
    unsigned u = __float_as_uint(val);
    u = (u + 0x7FFFu + ((u >> 16) & 1u)) >> 16;
    outv[j] = (unsigned short)u;
  }
#pragma unroll
  for (int j = 0; j < 8; ++j) ws[(long)e*8 + j] = outv[j];
}

#define LDSP 72

__global__ __launch_bounds__(64, 2) void tblock_kern(
    const float* __restrict__ x,
    const float* __restrict__ ubq, const float* __restrict__ ubk,
    const float* __restrict__ ubv, const float* __restrict__ ubp,
    const float* __restrict__ mbq, const float* __restrict__ mbk,
    const float* __restrict__ mbv, const float* __restrict__ mbp,
    const float* __restrict__ fb1, const float* __restrict__ fb2,
    const float* __restrict__ g1, const float* __restrict__ be1,
    const float* __restrict__ g2, const float* __restrict__ be2,
    const unsigned short* __restrict__ wf,
    float* __restrict__ outp)
{
  __shared__ float KS[2][16][LDSP];
  __shared__ float VS[2][16][LDSP];

  const int lane = threadIdx.x;
  const int t = lane & 15, g = lane >> 4;
  const long sbase = (long)blockIdx.x * 2048;   // 2 seqs * 1024 elems

  f32x4 R[2][4];
#pragma unroll
  for (int s = 0; s < 2; ++s)
#pragma unroll
    for (int m = 0; m < 4; ++m)
      R[s][m] = *(const f32x4*)(x + sbase + s*1024 + t*64 + 16*m + 4*g);

  auto ldA = [&](int base_bf16, int fbidx) -> bf16x8 {
    return *(const bf16x8*)(wf + base_bf16 + fbidx*512 + lane*8);
  };

  auto lnorm = [&](int s, const float* gp, const float* bp, BF bx[2]) {
    float sum = 0.f, sq = 0.f;
#pragma unroll
    for (int m = 0; m < 4; ++m)
#pragma unroll
      for (int r = 0; r < 4; ++r) { float v = R[s][m][r]; sum += v; sq += v*v; }
    sum += __shfl_xor(sum, 16); sum += __shfl_xor(sum, 32);
    sq  += __shfl_xor(sq , 16); sq  += __shfl_xor(sq , 32);
    float mean = sum * 0.015625f;
    float var  = sq  * 0.015625f - mean*mean;
    float rs = __builtin_amdgcn_rsqf(var + 1e-5f);
    float xn[4][4];
#pragma unroll
    for (int m = 0; m < 4; ++m) {
      f32x4 gm = *(const f32x4*)(gp + 16*m + 4*g);
      f32x4 bm = *(const f32x4*)(bp + 16*m + 4*g);
#pragma unroll
      for (int r = 0; r < 4; ++r)
        xn[m][r] = (R[s][m][r] - mean) * rs * gm[r] + bm[r];
    }
#pragma unroll
    for (int f = 0; f < 2; ++f)
#pragma unroll
      for (int mm = 0; mm < 2; ++mm) {
        bx[f].u[2*mm+0] = pk2(xn[2*f+mm][0], xn[2*f+mm][1]);
        bx[f].u[2*mm+1] = pk2(xn[2*f+mm][2], xn[2*f+mm][3]);
      }
  };

  auto attn = [&](int wq, int wk, int wv, int wp,
                  const float* bq, const float* bk, const float* bv,
                  const float* bpj, bool causal) {
    BF bx[2][2];
    lnorm(0, g1, be1, bx[0]);
    lnorm(1, g1, be1, bx[1]);

    // Q (kept in regs)
    f32x4 Q[2][4];
#pragma unroll
    for (int m = 0; m < 4; ++m) {
      bf16x8 a0 = ldA(wq, m*2+0), a1 = ldA(wq, m*2+1);
      f32x4 b4 = *(const f32x4*)(bq + 16*m + 4*g);
#pragma unroll
      for (int s = 0; s < 2; ++s) {
        f32x4 acc = {0.f,0.f,0.f,0.f};
        acc = __builtin_amdgcn_mfma_f32_16x16x32_bf16(a0, bx[s][0].v, acc, 0,0,0);
        acc = __builtin_amdgcn_mfma_f32_16x16x32_bf16(a1, bx[s][1].v, acc, 0,0,0);
#pragma unroll
        for (int r = 0; r < 4; ++r) acc[r] += b4[r];
        Q[s][m] = acc;
      }
    }
    // K -> LDS
#pragma unroll
    for (int m = 0; m < 4; ++m) {
      bf16x8 a0 = ldA(wk, m*2+0), a1 = ldA(wk, m*2+1);
      f32x4 b4 = *(const f32x4*)(bk + 16*m + 4*g);
#pragma unroll
      for (int s = 0; s < 2; ++s) {
        f32x4 acc = {0.f,0.f,0.f,0.f};
        acc = __builtin_amdgcn_mfma_f32_16x16x32_bf16(a0, bx[s][0].v, acc, 0,0,0);
        acc = __builtin_amdgcn_mfma_f32_16x16x32_bf16(a1, bx[s][1].v, acc, 0,0,0);
#pragma unroll
        for (int r = 0; r < 4; ++r) acc[r] += b4[r];
        *(f32x4*)&KS[s][t][16*m + 4*g] = acc;
      }
    }
    // V -> LDS
#pragma unroll
    for (int m = 0; m < 4; ++m) {
      bf16x8 a0 = ldA(wv, m*2+0), a1 = ldA(wv, m*2+1);
      f32x4 b4 = *(const f32x4*)(bv + 16*m + 4*g);
#pragma unroll
      for (int s = 0; s < 2; ++s) {
        f32x4 acc = {0.f,0.f,0.f,0.f};
        acc = __builtin_amdgcn_mfma_f32_16x16x32_bf16(a0, bx[s][0].v, acc, 0,0,0);
        acc = __builtin_amdgcn_mfma_f32_16x16x32_bf16(a1, bx[s][1].v, acc, 0,0,0);
#pragma unroll
        for (int r = 0; r < 4; ++r) acc[r] += b4[r];
        *(f32x4*)&VS[s][t][16*m + 4*g] = acc;
      }
    }

    // attention core per seq (VALU); head of reg-tile m is 2m + (g>>1)
#pragma unroll
    for (int s = 0; s < 2; ++s) {
      f32x4 O[4];
#pragma unroll
      for (int mp = 0; mp < 2; ++mp) {
        float e[2][16];
#pragma unroll
        for (int u = 0; u < 16; ++u) {
          f32x4 k0 = *(const f32x4*)&KS[s][u][32*mp + 4*g];
          f32x4 k1 = *(const f32x4*)&KS[s][u][32*mp + 16 + 4*g];
          f32x4 q0 = Q[s][2*mp+0], q1 = Q[s][2*mp+1];
          e[0][u] = q0[0]*k0[0] + q0[1]*k0[1] + q0[2]*k0[2] + q0[3]*k0[3];
          e[1][u] = q1[0]*k1[0] + q1[1]*k1[1] + q1[2]*k1[2] + q1[3]*k1[3];
        }
#pragma unroll
        for (int mm = 0; mm < 2; ++mm)
#pragma unroll
          for (int u = 0; u < 16; ++u)
            e[mm][u] += __shfl_xor(e[mm][u], 16);
        float rden[2];
#pragma unroll
        for (int mm = 0; mm < 2; ++mm) {
          float den = 0.f;
#pragma unroll
          for (int u = 0; u < 16; ++u) {
            // exp(dot * 8^-0.5) = exp2(dot * 8^-0.5 * log2e); no max-sub (scores tiny)
            float ex = (causal && (u > t)) ? 0.f
                     : exp2f(e[mm][u] * 0.51006977f);
            e[mm][u] = ex; den += ex;
          }
          rden[mm] = __builtin_amdgcn_rcpf(den);
        }
        f32x4 acc0 = {0.f,0.f,0.f,0.f}, acc1 = {0.f,0.f,0.f,0.f};
#pragma unroll
        for (int u = 0; u < 16; ++u) {
          f32x4 v0 = *(const f32x4*)&VS[s][u][32*mp + 4*g];
          f32x4 v1 = *(const f32x4*)&VS[s][u][32*mp + 16 + 4*g];
#pragma unroll
          for (int r = 0; r < 4; ++r) {
            acc0[r] += e[0][u] * v0[r];
            acc1[r] += e[1][u] * v1[r];
          }
        }
#pragma unroll
        for (int r = 0; r < 4; ++r) {
          O[2*mp+0][r] = acc0[r] * rden[0];
          O[2*mp+1][r] = acc1[r] * rden[1];
        }
      }
      // rebuild B-frags from O for the output projection
#pragma unroll
      for (int f = 0; f < 2; ++f)
#pragma unroll
        for (int mm = 0; mm < 2; ++mm) {
          bx[s][f].u[2*mm+0] = pk2(O[2*f+mm][0], O[2*f+mm][1]);
          bx[s][f].u[2*mm+1] = pk2(O[2*f+mm][2], O[2*f+mm][3]);
        }
    }
    // output projection + residual
#pragma unroll
    for (int m = 0; m < 4; ++m) {
      bf16x8 a0 = ldA(wp, m*2+0), a1 = ldA(wp, m*2+1);
      f32x4 b4 = *(const f32x4*)(bpj + 16*m + 4*g);
#pragma unroll
      for (int s = 0; s < 2; ++s) {
        f32x4 acc = {0.f,0.f,0.f,0.f};
        acc = __builtin_amdgcn_mfma_f32_16x16x32_bf16(a0, bx[s][0].v, acc, 0,0,0);
        acc = __builtin_amdgcn_mfma_f32_16x16x32_bf16(a1, bx[s][1].v, acc, 0,0,0);
#pragma unroll
        for (int r = 0; r < 4; ++r) R[s][m][r] += acc[r] + b4[r];
      }
    }
  };

  auto ffn = [&]() {
    BF bx[2][2];
    lnorm(0, g2, be2, bx[0]);
    lnorm(1, g2, be2, bx[1]);
    f32x4 yacc[2][4];
#pragma unroll
    for (int s = 0; s < 2; ++s)
#pragma unroll
      for (int m = 0; m < 4; ++m) yacc[s][m] = f32x4{0.f,0.f,0.f,0.f};
#pragma unroll
    for (int qt = 0; qt < 4; ++qt) {       // hidden in quarters of 64
      f32x4 h[2][4];
#pragma unroll
      for (int mt = 0; mt < 4; ++mt) {
        int ht = qt*4 + mt;
        bf16x8 a0 = ldA(OFF_F1, ht*2+0), a1 = ldA(OFF_F1, ht*2+1);
        f32x4 b4 = *(const f32x4*)(fb1 + 16*ht + 4*g);
#pragma unroll
        for (int s = 0; s < 2; ++s) {
          f32x4 acc = {0.f,0.f,0.f,0.f};
          acc = __builtin_amdgcn_mfma_f32_16x16x32_bf16(a0, bx[s][0].v, acc, 0,0,0);
          acc = __builtin_amdgcn_mfma_f32_16x16x32_bf16(a1, bx[s][1].v, acc, 0,0,0);
#pragma unroll
          for (int r = 0; r < 4; ++r) {
            float vv = acc[r] + b4[r];
            h[s][mt][r] = 0.5f * vv * (1.f + erff(vv * 0.70710678f)); // exact gelu
          }
        }
      }
      BF bh[2][2];
#pragma unroll
      for (int s = 0; s < 2; ++s)
#pragma unroll
        for (int q2 = 0; q2 < 2; ++q2) {
          bh[s][q2].u[0] = pk2(h[s][2*q2+0][0], h[s][2*q2+0][1]);
          bh[s][q2].u[1] = pk2(h[s][2*q2+0][2], h[s][2*q2+0][3]);
          bh[s][q2].u[2] = pk2(h[s][2*q2+1][0], h[s][2*q2+1][1]);
          bh[s][q2].u[3] = pk2(h[s][2*q2+1][2], h[s][2*q2+1][3]);
        }
#pragma unroll
      for (int m = 0; m < 4; ++m)
#pragma unroll
        for (int q2 = 0; q2 < 2; ++q2) {
          bf16x8 a = ldA(OFF_F2, m*8 + qt*2 + q2);
#pragma unroll
          for (int s = 0; s < 2; ++s)
            yacc[s][m] = __builtin_amdgcn_mfma_f32_16x16x32_bf16(a, bh[s][q2].v, yacc[s][m], 0,0,0);
        }
    }
#pragma unroll
    for (int m = 0; m < 4; ++m) {
      f32x4 b4 = *(const f32x4*)(fb2 + 16*m + 4*g);
#pragma unroll
      for (int s = 0; s < 2; ++s)
#pragma unroll
        for (int r = 0; r < 4; ++r) R[s][m][r] += yacc[s][m][r] + b4[r];
    }
  };

  attn(0*4096, 1*4096, 2*4096, 3*4096, ubq, ubk, ubv, ubp, false);
  ffn();
  attn(4*4096, 5*4096, 6*4096, 7*4096, mbq, mbk, mbv, mbp, true);
  ffn();

#pragma unroll
  for (int s = 0; s < 2; ++s)
#pragma unroll
    for (int m = 0; m < 4; ++m)
      *(f32x4*)(outp + sbase + s*1024 + t*64 + 16*m + 4*g) = R[s][m];
}

extern "C" void kernel_launch(void* const* d_in, const int* in_sizes, int n_in,
                              void* d_out, int out_size, void* d_ws, size_t ws_size,
                              hipStream_t stream) {
  const float* x   = (const float*)d_in[0];
  const float* uWq = (const float*)d_in[1];
  const float* ubq = (const float*)d_in[2];
  const float* uWk = (const float*)d_in[3];
  const float* ubk = (const float*)d_in[4];
  const float* uWv = (const float*)d_in[5];
  const float* ubv = (const float*)d_in[6];
  const float* uWp = (const float*)d_in[7];
  const float* ubp = (const float*)d_in[8];
  const float* mWq = (const float*)d_in[9];
  const float* mbq = (const float*)d_in[10];
  const float* mWk = (const float*)d_in[11];
  const float* mbk = (const float*)d_in[12];
  const float* mWv = (const float*)d_in[13];
  const float* mbv = (const float*)d_in[14];
  const float* mWp = (const float*)d_in[15];
  const float* mbp = (const float*)d_in[16];
  const float* fW1 = (const float*)d_in[17];
  const float* fb1 = (const float*)d_in[18];
  const float* fW2 = (const float*)d_in[19];
  const float* fb2 = (const float*)d_in[20];
  const float* g1  = (const float*)d_in[21];
  const float* be1 = (const float*)d_in[22];
  const float* g2  = (const float*)d_in[23];
  const float* be2 = (const float*)d_in[24];

  unsigned short* ws = (unsigned short*)d_ws;  // needs 131072 bytes

  prep_w<<<32, 256, 0, stream>>>(uWq, uWk, uWv, uWp, mWq, mWk, mWv, mWp,
                                 fW1, fW2, ws);
  tblock_kern<<<16384, 64, 0, stream>>>(x,
      ubq, ubk, ubv, ubp, mbq, mbk, mbv, mbp,
      fb1, fb2, g1, be1, g2, be2,
      (const unsigned short*)ws, (float*)d_out);
}